// Round 1
// baseline (308.111 us; speedup 1.0000x reference)
//
#include <hip/hip_runtime.h>
#include <math.h>

#define NANCH 87296
#define NF 4256        // 1000*4 + 256 finalists
#define CAPD 128       // max neighbors per column (expected max degree ~25)
#define NBINS 65536
#define NITER 16       // 15 scan iterations + initial keep (K_15 = F^16(ones))
#define BCAP 2048      // boundary-bin buffer per level

struct InPtrs {
    const float* cls[5];
    const float* reg[5];
    const float* loc;
};

// workspace layout
constexpr size_t SZ_HIST  = 5ull * NBINS * 4;                 // 1,310,720
constexpr size_t OFF_HIST = 0;
constexpr size_t OFF_CNT  = OFF_HIST + SZ_HIST;               // adjacency counters
constexpr size_t OFF_CTR  = OFF_CNT + (size_t)NF * 4;         // finCount, bCount[5]
constexpr size_t ZERO_SZ  = OFF_CTR + 64;                     // one memset covers all
constexpr size_t OFF_SBITS = ((ZERO_SZ + 255) / 256) * 256;
constexpr size_t OFF_CLSV  = OFF_SBITS + (size_t)NANCH * 4;
constexpr size_t OFF_PAR   = OFF_CLSV + (size_t)NANCH * 4;    // B*[5] @0..4, r*[5] @8..12
constexpr size_t OFF_FINK  = ((OFF_PAR + 64 + 255) / 256) * 256;
constexpr size_t OFF_BBUF  = OFF_FINK + (size_t)NF * 8;
constexpr size_t OFF_SBOX  = OFF_BBUF + 5ull * BCAP * 8;
constexpr size_t OFF_SSC   = OFF_SBOX + (size_t)NF * 16;
constexpr size_t OFF_SCV   = OFF_SSC + (size_t)NF * 4;
constexpr size_t OFF_SAR   = OFF_SCV + (size_t)NF * 4;
constexpr size_t OFF_NBR   = OFF_SAR + (size_t)NF * 4;
constexpr size_t WS_NEED   = OFF_NBR + (size_t)NF * CAPD * 2; // ~3.35 MB total

__device__ __forceinline__ void lvl_of(int a, int& lev, int& idx) {
    if (a < 65536)      { lev = 0; idx = a; }
    else if (a < 81920) { lev = 1; idx = a - 65536; }
    else if (a < 86016) { lev = 2; idx = a - 81920; }
    else if (a < 87040) { lev = 3; idx = a - 86016; }
    else                { lev = 4; idx = a - 87040; }
}

// order-preserving float->uint key (monotone; bigger float => bigger uint)
__device__ __forceinline__ unsigned int fkey(float f) {
    unsigned int u = __float_as_uint(f);
    return u ^ ((u & 0x80000000u) ? 0xFFFFFFFFu : 0x80000000u);
}
__device__ __forceinline__ float funkey(unsigned int k) {
    return __uint_as_float(k ^ ((k & 0x80000000u) ? 0x80000000u : 0xFFFFFFFFu));
}

// ---------------------------------------------------------------- K1
// per-anchor: max/argmax over 80 classes (first-occurrence), sigmoid score,
// validity (ps > 0.05), ordered key bits, 16-bit-bin histogram per level.
__global__ __launch_bounds__(256) void k1_score(InPtrs P, unsigned int* hist,
        unsigned int* sbits, unsigned int* clsv) {
    int a = blockIdx.x * blockDim.x + threadIdx.x;
    if (a >= NANCH) return;
    int lev, idx; lvl_of(a, lev, idx);
    const float4* row = (const float4*)(P.cls[lev] + (size_t)idx * 80);
    float best = -INFINITY; int bi = 0;
    #pragma unroll
    for (int q = 0; q < 20; ++q) {
        float4 v = row[q];
        if (v.x > best) { best = v.x; bi = 4*q + 0; }
        if (v.y > best) { best = v.y; bi = 4*q + 1; }
        if (v.z > best) { best = v.z; bi = 4*q + 2; }
        if (v.w > best) { best = v.w; bi = 4*q + 3; }
    }
    float score = 1.0f / (1.0f + expf(-best));   // mirror fp32 sigmoid chain
    unsigned int valid = (score > 0.05f) ? 1u : 0u;
    float psm = valid ? score : -1.0f;           // ps_m as in reference
    unsigned int sb = fkey(psm);
    sbits[a] = sb;
    clsv[a] = (unsigned int)(bi + 1) | (valid << 31);
    atomicAdd(&hist[(size_t)lev * NBINS + (sb >> 16)], 1u);
}

// ---------------------------------------------------------------- K2
// per level: descending scan of 65536 bins to find boundary bin B* and
// residual rank r* (how many to take from within the boundary bin).
__global__ __launch_bounds__(1024) void k2_scan(const unsigned int* hist,
        unsigned int* params) {
    int lev = blockIdx.x;
    unsigned int K = (lev == 4) ? 256u : 1000u;
    const unsigned int* h = hist + (size_t)lev * NBINS;
    __shared__ unsigned int seg[1024];
    __shared__ unsigned int suf[1024];
    int t = threadIdx.x;
    unsigned int s = 0;
    for (int b = 0; b < 64; ++b) s += h[t * 64 + b];
    seg[t] = s;
    suf[t] = s;
    __syncthreads();
    for (int off = 1; off < 1024; off <<= 1) {
        unsigned int v = suf[t];
        unsigned int add = (t + off < 1024) ? suf[t + off] : 0u;
        __syncthreads();
        suf[t] = v + add;
        __syncthreads();
    }
    unsigned int excl = suf[t] - seg[t];          // sum of all higher segments
    if (excl < K && excl + seg[t] >= K) {         // boundary in this segment
        unsigned int cum = excl;
        for (int b = 63; b >= 0; --b) {
            unsigned int c = h[t * 64 + b];
            if (cum + c >= K) {
                params[lev] = (unsigned int)(t * 64 + b);  // B*
                params[8 + lev] = K - cum;                 // r*
                break;
            }
            cum += c;
        }
    }
}

// ---------------------------------------------------------------- K3
// compact: bins strictly above B* -> finalists; bin == B* -> boundary buffer.
__global__ __launch_bounds__(256) void k3_compact(const unsigned int* sbits,
        const unsigned int* clsv, const unsigned int* params,
        unsigned long long* finKeys, unsigned int* finCount,
        unsigned long long* bBuf, unsigned int* bCount) {
    int a = blockIdx.x * blockDim.x + threadIdx.x;
    if (a >= NANCH) return;
    int lev, idx; lvl_of(a, lev, idx);
    unsigned int sb = sbits[a];
    unsigned int h16 = sb >> 16;
    unsigned int Bs = params[lev];
    if (h16 < Bs) return;
    unsigned int cv = clsv[a];
    unsigned int composite = ((unsigned int)lev << 16) | (unsigned int)idx;
    unsigned int inv = (~composite) & 0x7FFFFu;   // ties -> (level, idx) asc
    unsigned int low = (inv << 13) | ((cv >> 31) << 7) | (cv & 0x7Fu);
    unsigned long long key = ((unsigned long long)sb << 32) | low;
    if (h16 > Bs) {
        unsigned int p = atomicAdd(finCount, 1u);
        if (p < NF) finKeys[p] = key;
    } else {
        unsigned int p = atomicAdd(&bCount[lev], 1u);
        if (p < BCAP) bBuf[(size_t)lev * BCAP + p] = key;
    }
}

// ---------------------------------------------------------------- K4
// resolve boundary bins exactly: bitonic-sort each level's boundary list
// (full 64-bit keys => exact score+index tie-break), append top r*.
__global__ __launch_bounds__(1024) void k4_bound(const unsigned int* params,
        const unsigned long long* bBuf, const unsigned int* bCount,
        unsigned long long* finKeys, unsigned int* finCount) {
    __shared__ unsigned long long k[BCAP];
    int t = threadIdx.x;
    for (int lev = 0; lev < 5; ++lev) {
        unsigned int bc = bCount[lev];
        int n = (bc > BCAP) ? BCAP : (int)bc;
        int r = (int)params[8 + lev];
        if (r > n) r = n;
        int m = 1; while (m < n) m <<= 1;
        for (int i = t; i < m; i += 1024)
            k[i] = (i < n) ? bBuf[(size_t)lev * BCAP + i] : 0ull;
        __syncthreads();
        for (int len = 2; len <= m; len <<= 1) {
            for (int st = len >> 1; st > 0; st >>= 1) {
                for (int i = t; i < m; i += 1024) {
                    int j = i ^ st;
                    if (j > i) {
                        unsigned long long a = k[i], b = k[j];
                        bool up = ((i & len) == 0);         // descending overall
                        if (up ? (a < b) : (a > b)) { k[i] = b; k[j] = a; }
                    }
                }
                __syncthreads();
            }
        }
        for (int i = t; i < r; i += 1024) {
            unsigned int p = atomicAdd(finCount, 1u);
            if (p < NF) finKeys[p] = k[i];
        }
        __syncthreads();
    }
}

// ---------------------------------------------------------------- K5
// rank-by-counting sort (keys unique) + decode + clip + area/score.
__global__ __launch_bounds__(256) void k5_rank(InPtrs P,
        const unsigned long long* finKeys, float4* sBox, float* sScore,
        unsigned int* sCV, float* sArea) {
    __shared__ unsigned long long keys[NF];
    __shared__ unsigned int rnk[64];
    int t = threadIdx.x;
    for (int i = t; i < NF; i += 256) keys[i] = finKeys[i];
    if (t < 64) rnk[t] = 0;
    __syncthreads();
    int lf = t & 63;
    int seg = t >> 6;                      // 4 segments of 1064 (4*1064 = 4256)
    int f = blockIdx.x * 64 + lf;
    unsigned long long my = (f < NF) ? keys[f] : 0ull;
    if (f < NF) {
        unsigned int c = 0;
        int s0 = seg * 1064, s1 = s0 + 1064;
        for (int i = s0; i < s1; ++i) c += (keys[i] > my) ? 1u : 0u;
        atomicAdd(&rnk[lf], c);
    }
    __syncthreads();
    if (seg == 0 && f < NF) {
        unsigned int r = rnk[lf];
        unsigned int sb  = (unsigned int)(my >> 32);
        unsigned int low = (unsigned int)my;
        unsigned int composite = (~(low >> 13)) & 0x7FFFFu;
        int lev = composite >> 16;
        int idx = composite & 0xFFFF;
        float4 b = ((const float4*)P.reg[lev])[idx];
        float vy1 = P.loc[0], vx1 = P.loc[1], vy2 = P.loc[2], vx2 = P.loc[3];
        float y1 = fmaxf(b.x, vy1), x1 = fmaxf(b.y, vx1);
        float y2 = fminf(b.z, vy2), x2 = fminf(b.w, vx2);
        // exact fp32 (no FMA contraction) to match numpy reference bit-wise
        float area = __fmul_rn(fmaxf(y2 - y1, 0.0f), fmaxf(x2 - x1, 0.0f));
        unsigned int valid = (low >> 7) & 1u;
        sBox[r] = make_float4(y1, x1, y2, x2);
        sScore[r] = valid ? funkey(sb) : 0.0f;
        sCV[r] = (low & 0x7Fu) | (valid << 31);
        sArea[r] = area;
    }
}

// ---------------------------------------------------------------- K6
// sparse adjacency build over 64x64 tiles of the (i<j) triangle.
__global__ __launch_bounds__(256) void k6_adj(const float4* sBox,
        const float* sArea, unsigned int* cnt, unsigned short* nbr) {
    int jt = blockIdx.x, it = blockIdx.y;
    if (it > jt) return;
    __shared__ float4 cb[64]; __shared__ float ca[64];
    __shared__ float4 rb[64]; __shared__ float ra[64];
    int t = threadIdx.x;
    if (t < 64) {
        int j = jt * 64 + t;
        if (j < NF) { cb[t] = sBox[j]; ca[t] = sArea[j]; }
        int i = it * 64 + t;
        if (i < NF) { rb[t] = sBox[i]; ra[t] = sArea[i]; }
    }
    __syncthreads();
    int lj = t & 63;
    int j = jt * 64 + lj;
    if (j >= NF) return;
    float4 B = cb[lj]; float ab = ca[lj];
    for (int li = (t >> 6); li < 64; li += 4) {
        int i = it * 64 + li;
        if (i >= j) continue;                   // strict upper triangle
        float4 A = rb[li]; float aa = ra[li];
        float iy1 = fmaxf(A.x, B.x), ix1 = fmaxf(A.y, B.y);
        float iy2 = fminf(A.z, B.z), ix2 = fminf(A.w, B.w);
        float ih = fmaxf(iy2 - iy1, 0.0f), iw = fmaxf(ix2 - ix1, 0.0f);
        float inter = __fmul_rn(ih, iw);
        float uni = __fsub_rn(__fadd_rn(aa, ab), inter);
        float iou = __fdiv_rn(inter, fmaxf(uni, 1e-9f));
        if (iou > 0.5f) {
            unsigned int p = atomicAdd(&cnt[j], 1u);
            if (p < CAPD) nbr[(size_t)j * CAPD + p] = (unsigned short)i;
        }
    }
}

// ---------------------------------------------------------------- K7
// 16x sparse keep iteration (LDS double-buffer) + top-100 emit.
__global__ __launch_bounds__(1024) void k7_nms(InPtrs P, const float4* sBox,
        const float* sScore, const unsigned int* sCV, const unsigned int* cnt,
        const unsigned short* nbr, float* out) {
    __shared__ unsigned char bufA[NF];
    __shared__ unsigned char bufB[NF];
    __shared__ unsigned int csum[1024];
    __shared__ float ploc[6];
    int t = threadIdx.x;
    if (t < 6) ploc[t] = P.loc[t];
    for (int i = t; i < NF; i += 1024) bufA[i] = 1;
    __syncthreads();
    unsigned char* cur = bufA; unsigned char* nxt = bufB;
    for (int itr = 0; itr < NITER; ++itr) {
        for (int j = t; j < NF; j += 1024) {
            unsigned int d = cnt[j]; if (d > CAPD) d = CAPD;
            const unsigned short* nl = nbr + (size_t)j * CAPD;
            unsigned char kp = 1;
            for (unsigned int e = 0; e < d; ++e)
                if (cur[nl[e]]) { kp = 0; break; }
            nxt[j] = kp;
        }
        __syncthreads();
        unsigned char* tm = cur; cur = nxt; nxt = tm;
    }
    // final keep = k & valid; chunked prefix sum for output ranks
    const int CH = 5;
    int base = t * CH;
    unsigned char kf[CH];
    unsigned int sum = 0;
    #pragma unroll
    for (int q = 0; q < CH; ++q) {
        int j = base + q;
        unsigned char v = 0;
        if (j < NF) v = cur[j] & (unsigned char)(sCV[j] >> 31);
        kf[q] = v; sum += v;
    }
    csum[t] = sum;
    __syncthreads();
    for (int off = 1; off < 1024; off <<= 1) {
        unsigned int v = csum[t];
        unsigned int add = (t >= off) ? csum[t - off] : 0u;
        __syncthreads();
        csum[t] = v + add;
        __syncthreads();
    }
    unsigned int keptTot = csum[1023];
    unsigned int run = csum[t] - sum;     // kept before my first element
    float vy1 = ploc[0], vx1 = ploc[1], vy2 = ploc[2], vx2 = ploc[3];
    float sy = ploc[4] / fmaxf(vy2 - vy1, 1e-6f);
    float sx = ploc[5] / fmaxf(vx2 - vx1, 1e-6f);
    #pragma unroll
    for (int q = 0; q < CH; ++q) {
        int j = base + q;
        if (j >= NF) break;
        unsigned int slot = 0xFFFFFFFFu;
        float sc = 0.0f;
        if (kf[q]) {
            if (run < 100u) { slot = run; sc = sScore[j]; }
            run++;
        } else if (keptTot < 100u) {
            unsigned int nk = (unsigned int)j - run;       // non-kept before j
            unsigned int s2 = keptTot + nk;                // zeros fill in idx order
            if (s2 < 100u) { slot = s2; sc = 0.0f; }
        }
        if (slot < 100u) {
            float4 b = sBox[j];
            out[slot * 4 + 0] = (b.x - vy1) * sy;
            out[slot * 4 + 1] = (b.y - vx1) * sx;
            out[slot * 4 + 2] = (b.z - vy1) * sy;
            out[slot * 4 + 3] = (b.w - vx1) * sx;
            out[400 + slot] = (float)(sCV[j] & 0x7Fu);     // class as float
            out[500 + slot] = sc;
        }
    }
}

extern "C" void kernel_launch(void* const* d_in, const int* in_sizes, int n_in,
                              void* d_out, int out_size, void* d_ws, size_t ws_size,
                              hipStream_t stream) {
    (void)n_in; (void)out_size; (void)ws_size;
    InPtrs P;
    bool inter = (in_sizes[1] == 65536 * 4);   // dict order cls0,reg0,cls1,...
    for (int s = 0; s < 5; ++s) {
        P.cls[s] = (const float*)d_in[inter ? 2 * s : s];
        P.reg[s] = (const float*)d_in[inter ? 2 * s + 1 : 5 + s];
    }
    P.loc = (const float*)d_in[10];

    char* w = (char*)d_ws;
    unsigned int* hist   = (unsigned int*)(w + OFF_HIST);
    unsigned int* cnt    = (unsigned int*)(w + OFF_CNT);
    unsigned int* ctrs   = (unsigned int*)(w + OFF_CTR);   // [0]=finCount,[1..5]=bCount
    unsigned int* sbits  = (unsigned int*)(w + OFF_SBITS);
    unsigned int* clsv   = (unsigned int*)(w + OFF_CLSV);
    unsigned int* params = (unsigned int*)(w + OFF_PAR);
    unsigned long long* finKeys = (unsigned long long*)(w + OFF_FINK);
    unsigned long long* bBuf    = (unsigned long long*)(w + OFF_BBUF);
    float4* sBox  = (float4*)(w + OFF_SBOX);
    float* sScore = (float*)(w + OFF_SSC);
    unsigned int* sCV = (unsigned int*)(w + OFF_SCV);
    float* sArea  = (float*)(w + OFF_SAR);
    unsigned short* nbr = (unsigned short*)(w + OFF_NBR);

    hipMemsetAsync(d_ws, 0, ZERO_SZ, stream);
    k1_score<<<341, 256, 0, stream>>>(P, hist, sbits, clsv);
    k2_scan<<<5, 1024, 0, stream>>>(hist, params);
    k3_compact<<<341, 256, 0, stream>>>(sbits, clsv, params, finKeys, ctrs, bBuf, ctrs + 1);
    k4_bound<<<1, 1024, 0, stream>>>(params, bBuf, ctrs + 1, finKeys, ctrs);
    k5_rank<<<67, 256, 0, stream>>>(P, finKeys, sBox, sScore, sCV, sArea);
    dim3 g(67, 67);
    k6_adj<<<g, 256, 0, stream>>>(sBox, sArea, cnt, nbr);
    k7_nms<<<1, 1024, 0, stream>>>(P, sBox, sScore, sCV, cnt, nbr, (float*)d_out);
}